// Round 5
// baseline (317.132 us; speedup 1.0000x reference)
//
#include <hip/hip_runtime.h>
#include <cstdint>
#include <cstddef>

#define HIDDEN 1024
#define BATCH 4
#define SEQ 4096
#define M_ROWS (BATCH * SEQ)   // 16384
#define K_DIM 1024
#define SUBCHUNK 32
#define NSUB (SEQ / SUBCHUNK)  // 128

typedef __bf16 bf16_t;
typedef __bf16 v8bf __attribute__((ext_vector_type(8)));
typedef float v4f __attribute__((ext_vector_type(4)));

__device__ __forceinline__ unsigned short f32_to_bf16(float f) {
  unsigned int u = __float_as_uint(f);
  u += 0x7fffu + ((u >> 16) & 1u);   // round-to-nearest-even
  return (unsigned short)(u >> 16);
}
__device__ __forceinline__ float bf16_to_f32(unsigned short u) {
  return __uint_as_float((unsigned int)u << 16);
}

// ---- Convert (grid-stride, 2048 blocks): X fp32->bf16; Wb = (W0+W1)/8|W1|W2 ----
__global__ void convert_kernel(const float* __restrict__ X,
                               const float* __restrict__ W0,
                               const float* __restrict__ W1,
                               const float* __restrict__ W2,
                               unsigned short* __restrict__ Xb,
                               unsigned short* __restrict__ Wb) {
  for (int i = blockIdx.x * 256 + threadIdx.x; i < 4194304 + 786432;
       i += 2048 * 256) {
    float4 f;
    unsigned short* dst;
    int di;
    if (i < 4194304) {
      f = ((const float4*)X)[i];
      dst = Xb; di = i;
    } else {
      int j = i - 4194304;
      int mat = j >> 18;           // 262,144 float4 per matrix
      int off = j & 0x3FFFF;
      if (mat == 0) {
        float4 a = ((const float4*)W0)[off];
        float4 b = ((const float4*)W1)[off];
        f.x = (a.x + b.x) * 0.125f; f.y = (a.y + b.y) * 0.125f;
        f.z = (a.z + b.z) * 0.125f; f.w = (a.w + b.w) * 0.125f;
      } else {
        const float* src = (mat == 1) ? W1 : W2;
        f = ((const float4*)src)[off];
      }
      dst = Wb; di = j;
    }
    ushort4 u;
    u.x = f32_to_bf16(f.x); u.y = f32_to_bf16(f.y);
    u.z = f32_to_bf16(f.z); u.w = f32_to_bf16(f.w);
    ((ushort4*)dst)[di] = u;
  }
}

// ---- Phase 1: S = X @ Ws^T with fused in-subchunk cummax epilogue ----
// grid (8, 128): ntile x mtile. Writes Lp (bf16 in-subchunk cummax) + cmax.
// 128x128 tile, BK=32, swizzled LDS (R2: conflicts==0), global_load_lds w=16.
__global__ __launch_bounds__(256) void gemm_S_kernel(
    const bf16_t* __restrict__ A, const bf16_t* __restrict__ B,
    unsigned short* __restrict__ Lp, float* __restrict__ cmax) {
  __shared__ bf16_t As[128 * 32];
  __shared__ bf16_t Bs[128 * 32];

  const int tid = threadIdx.x;
  const int wave = tid >> 6;
  const int lane = tid & 63;
  const int wr = wave >> 1;
  const int wc = wave & 1;
  const int mtile0 = blockIdx.y * 128;
  const int ntile0 = blockIdx.x * 128;
  const int quad = lane >> 4;
  const int r16 = lane & 15;
  const int sw = quad ^ ((r16 >> 1) & 3);

  v4f acc[4][4];
#pragma unroll
  for (int i = 0; i < 4; ++i)
#pragma unroll
    for (int j = 0; j < 4; ++j) acc[i][j] = (v4f)(0.0f);

  for (int k0 = 0; k0 < K_DIM; k0 += 32) {
    __syncthreads();
#pragma unroll
    for (int jj = 0; jj < 2; ++jj) {
      int cid = wave * 128 + jj * 64 + lane;
      int m = cid >> 2;
      int kcg = (cid & 3) ^ ((cid >> 3) & 3);
      const bf16_t* gA = A + (size_t)(mtile0 + m) * K_DIM + k0 + kcg * 8;
      const bf16_t* gB = B + (size_t)(ntile0 + m) * K_DIM + k0 + kcg * 8;
      __builtin_amdgcn_global_load_lds(
          (__attribute__((address_space(1))) void*)gA,
          (__attribute__((address_space(3))) void*)((char*)As + (wave * 2 + jj) * 1024),
          16, 0, 0);
      __builtin_amdgcn_global_load_lds(
          (__attribute__((address_space(1))) void*)gB,
          (__attribute__((address_space(3))) void*)((char*)Bs + (wave * 2 + jj) * 1024),
          16, 0, 0);
    }
    __syncthreads();

    v8bf a[4], b[4];
#pragma unroll
    for (int i = 0; i < 4; ++i)
      a[i] = *(const v8bf*)&As[(wr * 64 + i * 16 + r16) * 32 + sw * 8];
#pragma unroll
    for (int j = 0; j < 4; ++j)
      b[j] = *(const v8bf*)&Bs[(wc * 64 + j * 16 + r16) * 32 + sw * 8];
#pragma unroll
    for (int i = 0; i < 4; ++i)
#pragma unroll
      for (int j = 0; j < 4; ++j)
        acc[i][j] = __builtin_amdgcn_mfma_f32_16x16x32_bf16(a[i], b[j], acc[i][j], 0, 0, 0);
  }

  // In-register inclusive cummax per 32-row subchunk (R3-verified).
  // C/D layout: col=lane&15, row=quad*4+reg (m89/m91).
  const int ncol0 = ntile0;
  const int bidx = mtile0 >> 12;
  const int sub0 = (mtile0 & 4095) >> 5;
#pragma unroll
  for (int ih = 0; ih < 2; ++ih) {
#pragma unroll
    for (int j = 0; j < 4; ++j) {
      float c0[4], c1[4];
      c0[0] = acc[ih * 2][j][0];
      c1[0] = acc[ih * 2 + 1][j][0];
#pragma unroll
      for (int r = 1; r < 4; ++r) {
        c0[r] = fmaxf(c0[r - 1], acc[ih * 2][j][r]);
        c1[r] = fmaxf(c1[r - 1], acc[ih * 2 + 1][j][r]);
      }
      float t0 = c0[3], t1 = c1[3], u;
      u = __shfl_up(t0, 16); if (quad >= 1) t0 = fmaxf(t0, u);
      u = __shfl_up(t0, 32); if (quad >= 2) t0 = fmaxf(t0, u);
      u = __shfl_up(t1, 16); if (quad >= 1) t1 = fmaxf(t1, u);
      u = __shfl_up(t1, 32); if (quad >= 2) t1 = fmaxf(t1, u);
      float e0 = __shfl_up(t0, 16); if (quad == 0) e0 = -INFINITY;
      float e1 = __shfl_up(t1, 16); if (quad == 0) e1 = -INFINITY;
      float T0 = __shfl(t0, 48 + r16);
      float T1 = __shfl(t1, 48 + r16);
      int col = ncol0 + wc * 64 + j * 16 + r16;
      int rowb = mtile0 + wr * 64 + ih * 32 + quad * 4;
#pragma unroll
      for (int r = 0; r < 4; ++r) {
        float L0 = fmaxf(c0[r], e0);
        float L1 = fmaxf(fmaxf(c1[r], e1), T0);
        Lp[(size_t)(rowb + r) * HIDDEN + col] = f32_to_bf16(L0);
        Lp[(size_t)(rowb + 16 + r) * HIDDEN + col] = f32_to_bf16(L1);
      }
      if (quad == 0) {
        int sub = sub0 + wr * 2 + ih;
        cmax[((size_t)bidx * NSUB + sub) * HIDDEN + col] = fmaxf(T0, T1);
      }
    }
  }
}

// ---- Phase 2: acc1 = X@W1^T, acc2 = X@W2^T (shared A staging), epilogue
// computes exclusive prefix from cmax, cm = max(pfx, Lp), writes
// out = (cm + acc2)*cm + acc1 directly.  grid (8, 128). ----
__global__ __launch_bounds__(256, 2) void gemm_out_kernel(
    const bf16_t* __restrict__ A, const bf16_t* __restrict__ B,
    const unsigned short* __restrict__ Lp, const float* __restrict__ cmax,
    float* __restrict__ out) {
  __shared__ bf16_t As[128 * 32];
  __shared__ bf16_t Bs1[128 * 32];
  __shared__ bf16_t Bs2[128 * 32];

  const int tid = threadIdx.x;
  const int wave = tid >> 6;
  const int lane = tid & 63;
  const int wr = wave >> 1;
  const int wc = wave & 1;
  const int mtile0 = blockIdx.y * 128;
  const int ntile0 = blockIdx.x * 128;
  const int quad = lane >> 4;
  const int r16 = lane & 15;
  const int sw = quad ^ ((r16 >> 1) & 3);

  v4f acc1[4][4], acc2[4][4];
#pragma unroll
  for (int i = 0; i < 4; ++i)
#pragma unroll
    for (int j = 0; j < 4; ++j) { acc1[i][j] = (v4f)(0.0f); acc2[i][j] = (v4f)(0.0f); }

  for (int k0 = 0; k0 < K_DIM; k0 += 32) {
    __syncthreads();
#pragma unroll
    for (int jj = 0; jj < 2; ++jj) {
      int cid = wave * 128 + jj * 64 + lane;
      int m = cid >> 2;
      int kcg = (cid & 3) ^ ((cid >> 3) & 3);
      const bf16_t* gA = A + (size_t)(mtile0 + m) * K_DIM + k0 + kcg * 8;
      const bf16_t* gB1 = B + (size_t)(1024 + ntile0 + m) * K_DIM + k0 + kcg * 8;
      const bf16_t* gB2 = B + (size_t)(2048 + ntile0 + m) * K_DIM + k0 + kcg * 8;
      __builtin_amdgcn_global_load_lds(
          (__attribute__((address_space(1))) void*)gA,
          (__attribute__((address_space(3))) void*)((char*)As + (wave * 2 + jj) * 1024),
          16, 0, 0);
      __builtin_amdgcn_global_load_lds(
          (__attribute__((address_space(1))) void*)gB1,
          (__attribute__((address_space(3))) void*)((char*)Bs1 + (wave * 2 + jj) * 1024),
          16, 0, 0);
      __builtin_amdgcn_global_load_lds(
          (__attribute__((address_space(1))) void*)gB2,
          (__attribute__((address_space(3))) void*)((char*)Bs2 + (wave * 2 + jj) * 1024),
          16, 0, 0);
    }
    __syncthreads();

    v8bf a[4], b1[4], b2[4];
#pragma unroll
    for (int i = 0; i < 4; ++i)
      a[i] = *(const v8bf*)&As[(wr * 64 + i * 16 + r16) * 32 + sw * 8];
#pragma unroll
    for (int j = 0; j < 4; ++j) {
      b1[j] = *(const v8bf*)&Bs1[(wc * 64 + j * 16 + r16) * 32 + sw * 8];
      b2[j] = *(const v8bf*)&Bs2[(wc * 64 + j * 16 + r16) * 32 + sw * 8];
    }
#pragma unroll
    for (int i = 0; i < 4; ++i)
#pragma unroll
      for (int j = 0; j < 4; ++j) {
        acc1[i][j] = __builtin_amdgcn_mfma_f32_16x16x32_bf16(a[i], b1[j], acc1[i][j], 0, 0, 0);
        acc2[i][j] = __builtin_amdgcn_mfma_f32_16x16x32_bf16(a[i], b2[j], acc2[i][j], 0, 0, 0);
      }
  }

  // Epilogue: exclusive prefix-max over subchunks for this thread's cols.
  const int bidx = mtile0 >> 12;
  const int sub0 = (mtile0 & 4095) >> 5;
  const int smax = sub0 + wr * 2;     // first sub this wave owns
  int cols[4];
#pragma unroll
  for (int j = 0; j < 4; ++j) cols[j] = ntile0 + wc * 64 + j * 16 + r16;

  float pfx0[4], pfx1[4], run[4];
#pragma unroll
  for (int j = 0; j < 4; ++j) run[j] = -INFINITY;
  const float* cp = cmax + (size_t)bidx * NSUB * HIDDEN;
  for (int s = 0; s <= smax + 1; ++s) {
    if (s == smax) {
#pragma unroll
      for (int j = 0; j < 4; ++j) pfx0[j] = run[j];
    }
    if (s == smax + 1) break;
#pragma unroll
    for (int j = 0; j < 4; ++j)
      run[j] = fmaxf(run[j], cp[(size_t)s * HIDDEN + cols[j]]);
  }
#pragma unroll
  for (int j = 0; j < 4; ++j) pfx1[j] = run[j];

  // cm = max(pfx, L); out = (cm + acc2)*cm + acc1
#pragma unroll
  for (int i = 0; i < 4; ++i) {
    const float* pf = (i >> 1) ? pfx1 : pfx0;
#pragma unroll
    for (int j = 0; j < 4; ++j) {
#pragma unroll
      for (int r = 0; r < 4; ++r) {
        int row = mtile0 + wr * 64 + i * 16 + quad * 4 + r;
        float L = bf16_to_f32(Lp[(size_t)row * HIDDEN + cols[j]]);
        float cm = fmaxf(pf[j], L);
        out[(size_t)row * HIDDEN + cols[j]] = (cm + acc2[i][j][r]) * cm + acc1[i][j][r];
      }
    }
  }
}

extern "C" void kernel_launch(void* const* d_in, const int* in_sizes, int n_in,
                              void* d_out, int out_size, void* d_ws, size_t ws_size,
                              hipStream_t stream) {
  const float* X = (const float*)d_in[0];
  const float* W0 = (const float*)d_in[1];
  const float* W1 = (const float*)d_in[2];
  const float* W2 = (const float*)d_in[3];
  float* out = (float*)d_out;

  // Workspace (~75.5 MiB):
  //   Xb   bf16 [16384][1024]   33,554,432 B
  //   Wb   bf16 [3072][1024]     6,291,456 B
  //   Lp   bf16 [16384][1024]   33,554,432 B   (in-subchunk cummax of S)
  //   cmax fp32 [4][128][1024]   2,097,152 B
  char* ws = (char*)d_ws;
  unsigned short* Xb = (unsigned short*)ws;
  unsigned short* Wb = (unsigned short*)(ws + 33554432);
  unsigned short* Lp = (unsigned short*)(ws + 33554432 + 6291456);
  float* cmax = (float*)(ws + 2 * 33554432 + 6291456);

  convert_kernel<<<2048, 256, 0, stream>>>(X, W0, W1, W2, Xb, Wb);

  dim3 ggrid(8, 128);  // n-tiles x m-tiles
  gemm_S_kernel<<<ggrid, 256, 0, stream>>>((const bf16_t*)Xb, (const bf16_t*)Wb,
                                           Lp, cmax);
  gemm_out_kernel<<<ggrid, 256, 0, stream>>>((const bf16_t*)Xb, (const bf16_t*)Wb,
                                             Lp, cmax, out);
}